// Round 15
// baseline (299.777 us; speedup 1.0000x reference)
//
#include <hip/hip_runtime.h>

using short8 = __attribute__((ext_vector_type(8))) short;
using f32x4  = __attribute__((ext_vector_type(4))) float;

#define BSHIFT 9
#define BSIZE  512     // nodes per bucket
#define CAP    12288   // max edges per bucket region (mean 8192)
#define CHUNK  2048    // edges per bin block

// ---------------- bf16 helpers ----------------

__device__ __forceinline__ unsigned int f2bf(float f) {
    unsigned int x = __float_as_uint(f);
    x += 0x7fffu + ((x >> 16) & 1u);  // round-to-nearest-even
    return x >> 16;
}
__device__ __forceinline__ unsigned int pack_bf2(float lo, float hi) {
    return f2bf(lo) | (f2bf(hi) << 16);
}

// u32 byte-offset gather helpers (saddr + 32-bit voffset addressing)
__device__ __forceinline__ uint2 ld_u2(const void* base, unsigned byte_off) {
    return *(const uint2*)((const char*)base + byte_off);
}
__device__ __forceinline__ float ld_f(const void* base, unsigned byte_off) {
    return *(const float*)((const char*)base + byte_off);
}

// ---------------- setup: W fp32 -> bf16 XOR-swizzled [c][k]; block 160 zeroes bfill --------

__global__ void wconv_kernel(const float* __restrict__ W1, const float* __restrict__ W2,
                             const float* __restrict__ W3, unsigned short* __restrict__ o1,
                             unsigned short* __restrict__ o2, unsigned short* __restrict__ o3,
                             int* __restrict__ bfill) {
    if (blockIdx.x == 160) {
        bfill[threadIdx.x] = 0;
        return;
    }
    int i = blockIdx.x * 256 + threadIdx.x;
    const float* W;
    unsigned short* o;
    int ncol, j;
    if (i < 16384)      { W = W1; o = o1; ncol = 128; j = i; }
    else if (i < 32768) { W = W2; o = o2; ncol = 128; j = i - 16384; }
    else if (i < 40960) { W = W3; o = o3; ncol = 64;  j = i - 32768; }
    else return;
    int k = j / ncol, c = j % ncol;
    int byte = (c * 256 + k * 2) ^ ((c & 7) << 4);
    o[byte >> 1] = (unsigned short)f2bf(W[j]);
}

// ---------------- graph prep: bucket binning (packed edges: src | dst_local<<17) ------------

__global__ __launch_bounds__(256) void bin_kernel(
    const int* __restrict__ src, const int* __restrict__ dst, int E,
    int* __restrict__ region, int* __restrict__ bfill) {
    __shared__ int lcnt[256];
    __shared__ int loff[256];
    __shared__ int gbase[256];
    __shared__ int stage[CHUNK];
    __shared__ unsigned short bOf[CHUNK];

    int t = threadIdx.x;
    int e0 = blockIdx.x * CHUNK;
    int cnt = min(CHUNK, E - e0);

    lcnt[t] = 0;
    __syncthreads();

    int s_[8], d_[8], p_[8];
#pragma unroll
    for (int i = 0; i < 8; i++) {
        int e = t + i * 256;
        if (e < cnt) {
            int s = src[e0 + e], d = dst[e0 + e];
            s_[i] = s;
            d_[i] = d;
            p_[i] = atomicAdd(&lcnt[d >> BSHIFT], 1);
        } else {
            d_[i] = -1;
        }
    }
    __syncthreads();

    int v = lcnt[t];
    loff[t] = v;
    __syncthreads();
    for (int off = 1; off < 256; off <<= 1) {
        int u = (t >= off) ? loff[t - off] : 0;
        __syncthreads();
        loff[t] += u;
        __syncthreads();
    }
    int ex = loff[t] - v;
    __syncthreads();
    loff[t] = ex;
    gbase[t] = (v > 0) ? atomicAdd(&bfill[t], v) : 0;
    __syncthreads();

#pragma unroll
    for (int i = 0; i < 8; i++) {
        if (d_[i] >= 0) {
            int b = d_[i] >> BSHIFT;
            int j = loff[b] + p_[i];
            stage[j] = s_[i] | ((d_[i] & (BSIZE - 1)) << 17);
            bOf[j] = (unsigned short)b;
        }
    }
    __syncthreads();

    for (int j = t; j < cnt; j += 256) {
        int b = bOf[j];
        int idx = gbase[b] + (j - loff[b]);
        if (idx < CAP) region[(size_t)b * CAP + idx] = stage[j];
    }
}

// per-bucket: LDS hist -> rinfo(beg,end)/dinv, scatter col into fixed-stride window b*CAP
__global__ __launch_bounds__(512) void build_kernel(
    const int* __restrict__ region, const int* __restrict__ bfill,
    int2* __restrict__ rinfo, float* __restrict__ dinv,
    int* __restrict__ col, int n) {
    __shared__ int cnt[BSIZE];
    __shared__ int excl[BSIZE];
    __shared__ int fill[BSIZE];
    int b = blockIdx.x;
    int t = threadIdx.x;
    int base = b * BSIZE;
    int ecnt = min(bfill[b], CAP);
    int ebase = b * CAP;
    const int* reg = region + (size_t)b * CAP;

    cnt[t] = 0;
    fill[t] = 0;
    __syncthreads();

    for (int i = t; i < ecnt; i += 512) atomicAdd(&cnt[reg[i] >> 17], 1);
    __syncthreads();

    int v = cnt[t];
    excl[t] = v;
    __syncthreads();
    for (int off = 1; off < 512; off <<= 1) {
        int u = (t >= off) ? excl[t - off] : 0;
        __syncthreads();
        excl[t] += u;
        __syncthreads();
    }
    int ex = excl[t] - v;
    __syncthreads();
    excl[t] = ex;
    __syncthreads();

    int node = base + t;
    if (node < n) {
        rinfo[node] = make_int2(ebase + ex, ebase + ex + v);
        dinv[node] = rsqrtf((float)(v + 1));  // +1 self loop
    }

    for (int i = t; i < ecnt; i += 512) {
        int p = reg[i];
        int li = p >> 17;
        int pos = atomicAdd(&fill[li], 1);
        col[ebase + excl[li] + pos] = p & 0x1FFFF;
    }
}

// ---------------- MFMA dense transform + int8 row quantization --------------------------------
// Y8[row] = uint8 row of NCOL feats: ub = round(v/s)+128, s = rowmax/127 stored in scl[row].
// v = (X @ W)[row][c] * dinv[row].

template <int NCOL, bool XF32>
__global__ __launch_bounds__(256) void mfma_gemm_kernel(const void* __restrict__ Xv,
                                                        const unsigned short* __restrict__ Wsw,
                                                        const float* __restrict__ dinv,
                                                        unsigned int* __restrict__ Y8,
                                                        float* __restrict__ scl, int n) {
    constexpr int CF = NCOL / 16;
    __shared__ unsigned short Wt[(size_t)NCOL * 128];

    int t = threadIdx.x;
    {   // flat copy of pre-swizzled W (NCOL*16 uint4)
        const uint4* Wg = (const uint4*)Wsw;
        uint4* Wl = (uint4*)Wt;
        for (int i = t; i < NCOL * 16; i += 256) Wl[i] = Wg[i];
    }
    __syncthreads();

    int wid = t >> 6, l = t & 63;
    int row0 = blockIdx.x * 128;
    int kq = l >> 4;
    const char* Wb = (const char*)Wt;

    for (int rt = 0; rt < 2; rt++) {
        int xr = row0 + (wid * 2 + rt) * 16 + (l & 15);
        int xrc = min(xr, n - 1);

        f32x4 acc[CF];
#pragma unroll
        for (int cf = 0; cf < CF; cf++) acc[cf] = (f32x4){0.f, 0.f, 0.f, 0.f};

#pragma unroll
        for (int ks = 0; ks < 4; ks++) {
            short8 bq;
            if (XF32) {
                const float* Xf = (const float*)Xv + (size_t)xrc * 128 + ks * 32 + kq * 8;
                float4 x0 = ((const float4*)Xf)[0];
                float4 x1 = ((const float4*)Xf)[1];
                unsigned int p0 = pack_bf2(x0.x, x0.y), p1 = pack_bf2(x0.z, x0.w);
                unsigned int p2 = pack_bf2(x1.x, x1.y), p3 = pack_bf2(x1.z, x1.w);
                uint4 u = make_uint4(p0, p1, p2, p3);
                bq = *(const short8*)&u;
            } else {
                const char* Xb = (const char*)Xv + (size_t)xrc * 256 + ks * 64 + kq * 16;
                bq = *(const short8*)Xb;
            }
#pragma unroll
            for (int cf = 0; cf < CF; cf++) {
                int c = cf * 16 + (l & 15);
                int byte = (c * 256 + ks * 64 + kq * 16) ^ ((c & 7) << 4);
                short8 aq = *(const short8*)(Wb + byte);
                acc[cf] = __builtin_amdgcn_mfma_f32_16x16x32_bf16(aq, bq, acc[cf], 0, 0, 0);
            }
        }

        if (xr < n) {
            float dsc = dinv[xr];
            float m = 0.f;
#pragma unroll
            for (int cf = 0; cf < CF; cf++) {
#pragma unroll
                for (int j = 0; j < 4; j++) {
                    float v = acc[cf][j] * dsc;
                    acc[cf][j] = v;
                    m = fmaxf(m, fabsf(v));
                }
            }
            // row absmax across the 4 kq lanes holding this row
            m = fmaxf(m, __shfl_xor(m, 16, 64));
            m = fmaxf(m, __shfl_xor(m, 32, 64));
            float s = m * (1.0f / 127.0f);
            float inv = (m > 0.f) ? 127.0f / m : 0.f;

            unsigned int* Yr = Y8 + (size_t)xr * (NCOL / 4);
#pragma unroll
            for (int cf = 0; cf < CF; cf++) {
                unsigned int pk = 0;
#pragma unroll
                for (int j = 0; j < 4; j++) {
                    int qv = (int)rintf(acc[cf][j] * inv) + 128;
                    qv = min(max(qv, 0), 255);
                    pk |= (unsigned int)qv << (8 * j);
                }
                Yr[cf * 4 + kq] = pk;
            }
            if (kq == 0) scl[xr] = s;
        }
    }
}

// accumulate 8 uint8 feats with scale, tracking sum of scales (agg64: offset corrected later)
#define ACCQ(v, sc)                                          \
    scs += (sc);                                             \
    a0 = fmaf((float)((v).x & 0xffu), (sc), a0);             \
    a1 = fmaf((float)(((v).x >> 8) & 0xffu), (sc), a1);      \
    a2 = fmaf((float)(((v).x >> 16) & 0xffu), (sc), a2);     \
    a3 = fmaf((float)((v).x >> 24), (sc), a3);               \
    a4 = fmaf((float)((v).y & 0xffu), (sc), a4);             \
    a5 = fmaf((float)(((v).y >> 8) & 0xffu), (sc), a5);      \
    a6 = fmaf((float)(((v).y >> 16) & 0xffu), (sc), a6);     \
    a7 = fmaf((float)((v).y >> 24), (sc), a7);

// same without scale-sum: the uniform +128*Σs*di shift cancels in LayerNorm (shift-invariant)
#define ACCQN(v, sc)                                         \
    a0 = fmaf((float)((v).x & 0xffu), (sc), a0);             \
    a1 = fmaf((float)(((v).x >> 8) & 0xffu), (sc), a1);      \
    a2 = fmaf((float)(((v).x >> 16) & 0xffu), (sc), a2);     \
    a3 = fmaf((float)((v).x >> 24), (sc), a3);               \
    a4 = fmaf((float)((v).y & 0xffu), (sc), a4);             \
    a5 = fmaf((float)(((v).y >> 8) & 0xffu), (sc), a5);      \
    a6 = fmaf((float)(((v).y >> 16) & 0xffu), (sc), a6);     \
    a7 = fmaf((float)((v).y >> 24), (sc), a7);

// select this quarter's src from 4 consecutive col values
#define QSEL(q, c0, c1, c2, c3) \
    (((q) & 2) ? (((q) & 1) ? (c3) : (c2)) : (((q) & 1) ? (c1) : (c0)))

// ---------------- fused aggregate + bias + LayerNorm + ReLU (128 int8 feats -> bf16) --------
// Quarter-wave q; lane l in [0,16) holds feats 8l..8l+7 (uint2 = 8 bytes of the 128B row).
// 16-edge main block: 4 independent gather+scl pairs in flight per lane (4-deep MLP).

__global__ __launch_bounds__(256) void agg_ln_kernel(
    const unsigned int* __restrict__ tmp, const float* __restrict__ scl,
    const int2* __restrict__ rinfo, const int* __restrict__ col,
    const float* __restrict__ dinv, const float* __restrict__ bias,
    const float* __restrict__ gamma, const float* __restrict__ beta,
    unsigned int* __restrict__ out, int n) {
    int wid = threadIdx.x >> 6;
    int lane = threadIdx.x & 63;
    int q = lane >> 4;
    int l = lane & 15;
    int stride = gridDim.x * 4;
    unsigned lb = (unsigned)l * 8u;  // lane byte offset within 128B row

    for (int node = blockIdx.x * 4 + wid; node < n; node += stride) {
        float di = dinv[node];
        int2 be = rinfo[node];
        int beg = __builtin_amdgcn_readfirstlane(be.x);
        int end = __builtin_amdgcn_readfirstlane(be.y);

        float a0 = 0.f, a1 = 0.f, a2 = 0.f, a3 = 0.f;
        float a4 = 0.f, a5 = 0.f, a6 = 0.f, a7 = 0.f;
        int e = beg;
        // 16-edge main block: 4 gathers in flight per lane
        for (; e + 15 < end; e += 16) {
            int s1, s2, s3, s4;
            {
                int c0 = col[e],      c1 = col[e + 1],  c2 = col[e + 2],  c3 = col[e + 3];
                int c4 = col[e + 4],  c5 = col[e + 5],  c6 = col[e + 6],  c7 = col[e + 7];
                int c8 = col[e + 8],  c9 = col[e + 9],  ca = col[e + 10], cb = col[e + 11];
                int cc = col[e + 12], cd = col[e + 13], ce = col[e + 14], cf = col[e + 15];
                s1 = QSEL(q, c0, c1, c2, c3);
                s2 = QSEL(q, c4, c5, c6, c7);
                s3 = QSEL(q, c8, c9, ca, cb);
                s4 = QSEL(q, cc, cd, ce, cf);
            }
            uint2 v1 = ld_u2(tmp, (unsigned)s1 * 128u + lb);
            uint2 v2 = ld_u2(tmp, (unsigned)s2 * 128u + lb);
            uint2 v3 = ld_u2(tmp, (unsigned)s3 * 128u + lb);
            uint2 v4 = ld_u2(tmp, (unsigned)s4 * 128u + lb);
            float f1 = ld_f(scl, (unsigned)s1 * 4u);
            float f2 = ld_f(scl, (unsigned)s2 * 4u);
            float f3 = ld_f(scl, (unsigned)s3 * 4u);
            float f4 = ld_f(scl, (unsigned)s4 * 4u);
            ACCQN(v1, f1)
            ACCQN(v2, f2)
            ACCQN(v3, f3)
            ACCQN(v4, f4)
        }
        // 8-edge block (2 in flight)
        if (e + 7 < end) {
            int c0 = col[e], c1 = col[e + 1], c2 = col[e + 2], c3 = col[e + 3];
            int c4 = col[e + 4], c5 = col[e + 5], c6 = col[e + 6], c7 = col[e + 7];
            int s1 = QSEL(q, c0, c1, c2, c3);
            int s2 = QSEL(q, c4, c5, c6, c7);
            uint2 v1 = ld_u2(tmp, (unsigned)s1 * 128u + lb);
            uint2 v2 = ld_u2(tmp, (unsigned)s2 * 128u + lb);
            float f1 = ld_f(scl, (unsigned)s1 * 4u);
            float f2 = ld_f(scl, (unsigned)s2 * 4u);
            ACCQN(v1, f1)
            ACCQN(v2, f2)
            e += 8;
        }
        // 4-edge block
        if (e + 3 < end) {
            int c0 = col[e], c1 = col[e + 1], c2 = col[e + 2], c3 = col[e + 3];
            int s = QSEL(q, c0, c1, c2, c3);
            uint2 v = ld_u2(tmp, (unsigned)s * 128u + lb);
            float f = ld_f(scl, (unsigned)s * 4u);
            ACCQN(v, f)
            e += 4;
        }
        int rem = end - e;  // 0..3
        if (q < rem) {
            int s = col[e + q];
            uint2 v = ld_u2(tmp, (unsigned)s * 128u + lb);
            float f = ld_f(scl, (unsigned)s * 4u);
            ACCQN(v, f)
        }
        if (q == 3) {  // self loop
            uint2 v = ld_u2(tmp, (unsigned)node * 128u + lb);
            float f = ld_f(scl, (unsigned)node * 4u);
            ACCQN(v, f)
        }

        // combine quarters
        a0 += __shfl_xor(a0, 16, 64); a1 += __shfl_xor(a1, 16, 64);
        a2 += __shfl_xor(a2, 16, 64); a3 += __shfl_xor(a3, 16, 64);
        a4 += __shfl_xor(a4, 16, 64); a5 += __shfl_xor(a5, 16, 64);
        a6 += __shfl_xor(a6, 16, 64); a7 += __shfl_xor(a7, 16, 64);
        a0 += __shfl_xor(a0, 32, 64); a1 += __shfl_xor(a1, 32, 64);
        a2 += __shfl_xor(a2, 32, 64); a3 += __shfl_xor(a3, 32, 64);
        a4 += __shfl_xor(a4, 32, 64); a5 += __shfl_xor(a5, 32, 64);
        a6 += __shfl_xor(a6, 32, 64); a7 += __shfl_xor(a7, 32, 64);

        float4 b0 = ((const float4*)bias)[2 * l];
        float4 b1 = ((const float4*)bias)[2 * l + 1];
        a0 = fmaf(a0, di, b0.x); a1 = fmaf(a1, di, b0.y);
        a2 = fmaf(a2, di, b0.z); a3 = fmaf(a3, di, b0.w);
        a4 = fmaf(a4, di, b1.x); a5 = fmaf(a5, di, b1.y);
        a6 = fmaf(a6, di, b1.z); a7 = fmaf(a7, di, b1.w);

        // LayerNorm across 16 lanes (all quarters hold identical data)
        float s8 = a0 + a1 + a2 + a3 + a4 + a5 + a6 + a7;
#pragma unroll
        for (int m = 1; m < 16; m <<= 1) s8 += __shfl_xor(s8, m, 64);
        float mu = s8 * (1.0f / 128.0f);
        float d0 = a0 - mu, d1 = a1 - mu, d2 = a2 - mu, d3 = a3 - mu;
        float d4 = a4 - mu, d5 = a5 - mu, d6 = a6 - mu, d7 = a7 - mu;
        float vv = d0 * d0 + d1 * d1 + d2 * d2 + d3 * d3 +
                   d4 * d4 + d5 * d5 + d6 * d6 + d7 * d7;
#pragma unroll
        for (int m = 1; m < 16; m <<= 1) vv += __shfl_xor(vv, m, 64);
        float r = rsqrtf(vv * (1.0f / 128.0f) + 1e-5f);

        if (lane < 16) {
            float4 g0 = ((const float4*)gamma)[2 * l];
            float4 g1 = ((const float4*)gamma)[2 * l + 1];
            float4 e0 = ((const float4*)beta)[2 * l];
            float4 e1 = ((const float4*)beta)[2 * l + 1];
            float o0 = fmaxf(fmaf(d0 * r, g0.x, e0.x), 0.f);
            float o1 = fmaxf(fmaf(d1 * r, g0.y, e0.y), 0.f);
            float o2 = fmaxf(fmaf(d2 * r, g0.z, e0.z), 0.f);
            float o3 = fmaxf(fmaf(d3 * r, g0.w, e0.w), 0.f);
            float o4 = fmaxf(fmaf(d4 * r, g1.x, e1.x), 0.f);
            float o5 = fmaxf(fmaf(d5 * r, g1.y, e1.y), 0.f);
            float o6 = fmaxf(fmaf(d6 * r, g1.z, e1.z), 0.f);
            float o7 = fmaxf(fmaf(d7 * r, g1.w, e1.w), 0.f);
            uint4 o = make_uint4(pack_bf2(o0, o1), pack_bf2(o2, o3),
                                 pack_bf2(o4, o5), pack_bf2(o6, o7));
            ((uint4*)out)[(size_t)node * 16 + l] = o;
        }
    }
}

// ---------------- final aggregate + bias (64 int8 feats -> fp32, no LN) ----------------
// Eighth-wave oc; lane l in [0,8) holds feats 8l..8l+7 (uint2 of the 64B row).

__global__ __launch_bounds__(256) void agg64_kernel(
    const unsigned int* __restrict__ tmp, const float* __restrict__ scl,
    const int2* __restrict__ rinfo, const int* __restrict__ col,
    const float* __restrict__ dinv, const float* __restrict__ bias,
    float* __restrict__ out, int n) {
    int wid = threadIdx.x >> 6;
    int lane = threadIdx.x & 63;
    int oc = lane >> 3;
    int l = lane & 7;
    int stride = gridDim.x * 4;
    unsigned lb = (unsigned)l * 8u;  // lane byte offset within 64B row

    for (int node = blockIdx.x * 4 + wid; node < n; node += stride) {
        float di = dinv[node];
        int2 be = rinfo[node];
        int beg = __builtin_amdgcn_readfirstlane(be.x);
        int end = __builtin_amdgcn_readfirstlane(be.y);

        float a0 = 0.f, a1 = 0.f, a2 = 0.f, a3 = 0.f;
        float a4 = 0.f, a5 = 0.f, a6 = 0.f, a7 = 0.f;
        float scs = 0.f;
        int e = beg;
#pragma unroll 2
        for (; e + 7 < end; e += 8) {
            int c0 = col[e], c1 = col[e + 1], c2 = col[e + 2], c3 = col[e + 3];
            int c4 = col[e + 4], c5 = col[e + 5], c6 = col[e + 6], c7 = col[e + 7];
            int sa = (oc & 1) ? c1 : c0;
            int sb = (oc & 1) ? c3 : c2;
            int sc_ = (oc & 1) ? c5 : c4;
            int sd = (oc & 1) ? c7 : c6;
            int sab = (oc & 2) ? sb : sa;
            int scd = (oc & 2) ? sd : sc_;
            int s = (oc & 4) ? scd : sab;
            uint2 v = ld_u2(tmp, (unsigned)s * 64u + lb);
            float f = ld_f(scl, (unsigned)s * 4u);
            ACCQ(v, f)
        }
        int rem = end - e;  // 0..7, oc==7 never takes tail
        if (oc < rem) {
            int s = col[e + oc];
            uint2 v = ld_u2(tmp, (unsigned)s * 64u + lb);
            float f = ld_f(scl, (unsigned)s * 4u);
            ACCQ(v, f)
        }
        if (oc == 7) {  // self loop
            uint2 v = ld_u2(tmp, (unsigned)node * 64u + lb);
            float f = ld_f(scl, (unsigned)node * 4u);
            ACCQ(v, f)
        }
        a0 = fmaf(-128.f, scs, a0); a1 = fmaf(-128.f, scs, a1);
        a2 = fmaf(-128.f, scs, a2); a3 = fmaf(-128.f, scs, a3);
        a4 = fmaf(-128.f, scs, a4); a5 = fmaf(-128.f, scs, a5);
        a6 = fmaf(-128.f, scs, a6); a7 = fmaf(-128.f, scs, a7);

        a0 += __shfl_xor(a0, 8, 64);  a1 += __shfl_xor(a1, 8, 64);
        a2 += __shfl_xor(a2, 8, 64);  a3 += __shfl_xor(a3, 8, 64);
        a4 += __shfl_xor(a4, 8, 64);  a5 += __shfl_xor(a5, 8, 64);
        a6 += __shfl_xor(a6, 8, 64);  a7 += __shfl_xor(a7, 8, 64);
        a0 += __shfl_xor(a0, 16, 64); a1 += __shfl_xor(a1, 16, 64);
        a2 += __shfl_xor(a2, 16, 64); a3 += __shfl_xor(a3, 16, 64);
        a4 += __shfl_xor(a4, 16, 64); a5 += __shfl_xor(a5, 16, 64);
        a6 += __shfl_xor(a6, 16, 64); a7 += __shfl_xor(a7, 16, 64);
        a0 += __shfl_xor(a0, 32, 64); a1 += __shfl_xor(a1, 32, 64);
        a2 += __shfl_xor(a2, 32, 64); a3 += __shfl_xor(a3, 32, 64);
        a4 += __shfl_xor(a4, 32, 64); a5 += __shfl_xor(a5, 32, 64);
        a6 += __shfl_xor(a6, 32, 64); a7 += __shfl_xor(a7, 32, 64);

        if (lane < 8) {
            float4 b0 = ((const float4*)bias)[2 * l];
            float4 b1 = ((const float4*)bias)[2 * l + 1];
            float4 o0, o1;
            o0.x = fmaf(a0, di, b0.x); o0.y = fmaf(a1, di, b0.y);
            o0.z = fmaf(a2, di, b0.z); o0.w = fmaf(a3, di, b0.w);
            o1.x = fmaf(a4, di, b1.x); o1.y = fmaf(a5, di, b1.y);
            o1.z = fmaf(a6, di, b1.z); o1.w = fmaf(a7, di, b1.w);
            ((float4*)out)[(size_t)node * 16 + 2 * l] = o0;
            ((float4*)out)[(size_t)node * 16 + 2 * l + 1] = o1;
        }
    }
}

// ---------------- launch ----------------

extern "C" void kernel_launch(void* const* d_in, const int* in_sizes, int n_in,
                              void* d_out, int out_size, void* d_ws, size_t ws_size,
                              hipStream_t stream) {
    const float* x   = (const float*)d_in[0];
    const int*   ei  = (const int*)d_in[1];
    const float* W1  = (const float*)d_in[2];
    const float* b1  = (const float*)d_in[3];
    const float* g1  = (const float*)d_in[4];
    const float* be1 = (const float*)d_in[5];
    const float* W2  = (const float*)d_in[6];
    const float* b2  = (const float*)d_in[7];
    const float* g2  = (const float*)d_in[8];
    const float* be2 = (const float*)d_in[9];
    const float* W3  = (const float*)d_in[10];
    const float* b3  = (const float*)d_in[11];

    int n = in_sizes[0] / 128;
    int E = in_sizes[1] / 2;
    const int* src = ei;
    const int* dst = ei + E;
    int nbuck = (n + BSIZE - 1) / BSIZE;  // 196 for n=100000 (n must be < 131072)

    char* p = (char*)d_ws;
    auto alloc = [&](size_t bytes) {
        void* q = (void*)p;
        p += (bytes + 255) & ~(size_t)255;
        return q;
    };
    int*   bfill   = (int*)alloc(256 * 4);
    int2*  rinfo   = (int2*)alloc((size_t)n * 8);
    float* dinv    = (float*)alloc((size_t)n * 4);
    float* scl     = (float*)alloc((size_t)n * 4);
    unsigned short* wsw1 = (unsigned short*)alloc(128 * 128 * 2);
    unsigned short* wsw2 = (unsigned short*)alloc(128 * 128 * 2);
    unsigned short* wsw3 = (unsigned short*)alloc(64 * 128 * 2);
    int*   region  = (int*)alloc((size_t)nbuck * CAP * 4);
    int*   col     = (int*)alloc((size_t)nbuck * CAP * 4);
    unsigned int* bufA = (unsigned int*)alloc((size_t)n * 64 * 4);  // LN out, n x 128 bf16
    unsigned int* bufB = (unsigned int*)alloc((size_t)n * 32 * 4);  // GEMM out, n x 128 int8

    // setup: W convert (blocks 0..159) + bfill zero (block 160)
    wconv_kernel<<<161, 256, 0, stream>>>(W1, W2, W3, wsw1, wsw2, wsw3, bfill);

    int bin_blocks = (E + CHUNK - 1) / CHUNK;
    bin_kernel<<<bin_blocks, 256, 0, stream>>>(src, dst, E, region, bfill);
    build_kernel<<<nbuck, 512, 0, stream>>>(region, bfill, rinfo, dinv, col, n);

    int gemm_blocks = (n + 127) / 128;
    int agg_blocks = 2048;  // exactly 8 blocks/CU = 32 waves resident in one round

    // layer 1
    mfma_gemm_kernel<128, true><<<gemm_blocks, 256, 0, stream>>>(x, wsw1, dinv, bufB, scl, n);
    agg_ln_kernel<<<agg_blocks, 256, 0, stream>>>(bufB, scl, rinfo, col, dinv, b1, g1, be1, bufA, n);

    // layer 2
    mfma_gemm_kernel<128, false><<<gemm_blocks, 256, 0, stream>>>(bufA, wsw2, dinv, bufB, scl, n);
    agg_ln_kernel<<<agg_blocks, 256, 0, stream>>>(bufB, scl, rinfo, col, dinv, b2, g2, be2, bufA, n);

    // layer 3
    mfma_gemm_kernel<64, false><<<gemm_blocks, 256, 0, stream>>>(bufA, wsw3, dinv, bufB, scl, n);
    agg64_kernel<<<agg_blocks, 256, 0, stream>>>(bufB, scl, rinfo, col, dinv, b3, (float*)d_out, n);
}

// Round 16
// 244.897 us; speedup vs baseline: 1.2241x; 1.2241x over previous
//
#include <hip/hip_runtime.h>

using short8 = __attribute__((ext_vector_type(8))) short;
using f32x4  = __attribute__((ext_vector_type(4))) float;

#define BSHIFT 9
#define BSIZE  512     // nodes per bucket
#define CAP    12288   // max edges per bucket region (mean 8192)
#define CHUNK  2048    // edges per bin block

// ---------------- bf16 helpers ----------------

__device__ __forceinline__ unsigned int f2bf(float f) {
    unsigned int x = __float_as_uint(f);
    x += 0x7fffu + ((x >> 16) & 1u);  // round-to-nearest-even
    return x >> 16;
}
__device__ __forceinline__ unsigned int pack_bf2(float lo, float hi) {
    return f2bf(lo) | (f2bf(hi) << 16);
}

// u32 byte-offset gather helpers (saddr + 32-bit voffset addressing)
__device__ __forceinline__ uint2 ld_u2(const void* base, unsigned byte_off) {
    return *(const uint2*)((const char*)base + byte_off);
}
__device__ __forceinline__ float ld_f(const void* base, unsigned byte_off) {
    return *(const float*)((const char*)base + byte_off);
}

// ---------------- setup: W fp32 -> bf16 XOR-swizzled [c][k]; block 160 zeroes bfill --------

__global__ void wconv_kernel(const float* __restrict__ W1, const float* __restrict__ W2,
                             const float* __restrict__ W3, unsigned short* __restrict__ o1,
                             unsigned short* __restrict__ o2, unsigned short* __restrict__ o3,
                             int* __restrict__ bfill) {
    if (blockIdx.x == 160) {
        bfill[threadIdx.x] = 0;
        return;
    }
    int i = blockIdx.x * 256 + threadIdx.x;
    const float* W;
    unsigned short* o;
    int ncol, j;
    if (i < 16384)      { W = W1; o = o1; ncol = 128; j = i; }
    else if (i < 32768) { W = W2; o = o2; ncol = 128; j = i - 16384; }
    else if (i < 40960) { W = W3; o = o3; ncol = 64;  j = i - 32768; }
    else return;
    int k = j / ncol, c = j % ncol;
    int byte = (c * 256 + k * 2) ^ ((c & 7) << 4);
    o[byte >> 1] = (unsigned short)f2bf(W[j]);
}

// ---------------- graph prep: bucket binning (packed edges: src | dst_local<<17) ------------

__global__ __launch_bounds__(256) void bin_kernel(
    const int* __restrict__ src, const int* __restrict__ dst, int E,
    int* __restrict__ region, int* __restrict__ bfill) {
    __shared__ int lcnt[256];
    __shared__ int loff[256];
    __shared__ int gbase[256];
    __shared__ int stage[CHUNK];
    __shared__ unsigned short bOf[CHUNK];

    int t = threadIdx.x;
    int e0 = blockIdx.x * CHUNK;
    int cnt = min(CHUNK, E - e0);

    lcnt[t] = 0;
    __syncthreads();

    int s_[8], d_[8], p_[8];
#pragma unroll
    for (int i = 0; i < 8; i++) {
        int e = t + i * 256;
        if (e < cnt) {
            int s = src[e0 + e], d = dst[e0 + e];
            s_[i] = s;
            d_[i] = d;
            p_[i] = atomicAdd(&lcnt[d >> BSHIFT], 1);
        } else {
            d_[i] = -1;
        }
    }
    __syncthreads();

    int v = lcnt[t];
    loff[t] = v;
    __syncthreads();
    for (int off = 1; off < 256; off <<= 1) {
        int u = (t >= off) ? loff[t - off] : 0;
        __syncthreads();
        loff[t] += u;
        __syncthreads();
    }
    int ex = loff[t] - v;
    __syncthreads();
    loff[t] = ex;
    gbase[t] = (v > 0) ? atomicAdd(&bfill[t], v) : 0;
    __syncthreads();

#pragma unroll
    for (int i = 0; i < 8; i++) {
        if (d_[i] >= 0) {
            int b = d_[i] >> BSHIFT;
            int j = loff[b] + p_[i];
            stage[j] = s_[i] | ((d_[i] & (BSIZE - 1)) << 17);
            bOf[j] = (unsigned short)b;
        }
    }
    __syncthreads();

    for (int j = t; j < cnt; j += 256) {
        int b = bOf[j];
        int idx = gbase[b] + (j - loff[b]);
        if (idx < CAP) region[(size_t)b * CAP + idx] = stage[j];
    }
}

// per-bucket: LDS hist -> rinfo(beg,end)/dinv, scatter col into fixed-stride window b*CAP
__global__ __launch_bounds__(512) void build_kernel(
    const int* __restrict__ region, const int* __restrict__ bfill,
    int2* __restrict__ rinfo, float* __restrict__ dinv,
    int* __restrict__ col, int n) {
    __shared__ int cnt[BSIZE];
    __shared__ int excl[BSIZE];
    __shared__ int fill[BSIZE];
    int b = blockIdx.x;
    int t = threadIdx.x;
    int base = b * BSIZE;
    int ecnt = min(bfill[b], CAP);
    int ebase = b * CAP;
    const int* reg = region + (size_t)b * CAP;

    cnt[t] = 0;
    fill[t] = 0;
    __syncthreads();

    for (int i = t; i < ecnt; i += 512) atomicAdd(&cnt[reg[i] >> 17], 1);
    __syncthreads();

    int v = cnt[t];
    excl[t] = v;
    __syncthreads();
    for (int off = 1; off < 512; off <<= 1) {
        int u = (t >= off) ? excl[t - off] : 0;
        __syncthreads();
        excl[t] += u;
        __syncthreads();
    }
    int ex = excl[t] - v;
    __syncthreads();
    excl[t] = ex;
    __syncthreads();

    int node = base + t;
    if (node < n) {
        rinfo[node] = make_int2(ebase + ex, ebase + ex + v);
        dinv[node] = rsqrtf((float)(v + 1));  // +1 self loop
    }

    for (int i = t; i < ecnt; i += 512) {
        int p = reg[i];
        int li = p >> 17;
        int pos = atomicAdd(&fill[li], 1);
        col[ebase + excl[li] + pos] = p & 0x1FFFF;
    }
}

// ---------------- MFMA dense transform + int8 row quantization --------------------------------
// Y8[row] = uint8 row of NCOL feats: ub = round(v/s)+128, s = rowmax/127 stored in scl[row].
// v = (X @ W)[row][c] * dinv[row].

template <int NCOL, bool XF32>
__global__ __launch_bounds__(256) void mfma_gemm_kernel(const void* __restrict__ Xv,
                                                        const unsigned short* __restrict__ Wsw,
                                                        const float* __restrict__ dinv,
                                                        unsigned int* __restrict__ Y8,
                                                        float* __restrict__ scl, int n) {
    constexpr int CF = NCOL / 16;
    __shared__ unsigned short Wt[(size_t)NCOL * 128];

    int t = threadIdx.x;
    {   // flat copy of pre-swizzled W (NCOL*16 uint4)
        const uint4* Wg = (const uint4*)Wsw;
        uint4* Wl = (uint4*)Wt;
        for (int i = t; i < NCOL * 16; i += 256) Wl[i] = Wg[i];
    }
    __syncthreads();

    int wid = t >> 6, l = t & 63;
    int row0 = blockIdx.x * 128;
    int kq = l >> 4;
    const char* Wb = (const char*)Wt;

    for (int rt = 0; rt < 2; rt++) {
        int xr = row0 + (wid * 2 + rt) * 16 + (l & 15);
        int xrc = min(xr, n - 1);

        f32x4 acc[CF];
#pragma unroll
        for (int cf = 0; cf < CF; cf++) acc[cf] = (f32x4){0.f, 0.f, 0.f, 0.f};

#pragma unroll
        for (int ks = 0; ks < 4; ks++) {
            short8 bq;
            if (XF32) {
                const float* Xf = (const float*)Xv + (size_t)xrc * 128 + ks * 32 + kq * 8;
                float4 x0 = ((const float4*)Xf)[0];
                float4 x1 = ((const float4*)Xf)[1];
                unsigned int p0 = pack_bf2(x0.x, x0.y), p1 = pack_bf2(x0.z, x0.w);
                unsigned int p2 = pack_bf2(x1.x, x1.y), p3 = pack_bf2(x1.z, x1.w);
                uint4 u = make_uint4(p0, p1, p2, p3);
                bq = *(const short8*)&u;
            } else {
                const char* Xb = (const char*)Xv + (size_t)xrc * 256 + ks * 64 + kq * 16;
                bq = *(const short8*)Xb;
            }
#pragma unroll
            for (int cf = 0; cf < CF; cf++) {
                int c = cf * 16 + (l & 15);
                int byte = (c * 256 + ks * 64 + kq * 16) ^ ((c & 7) << 4);
                short8 aq = *(const short8*)(Wb + byte);
                acc[cf] = __builtin_amdgcn_mfma_f32_16x16x32_bf16(aq, bq, acc[cf], 0, 0, 0);
            }
        }

        if (xr < n) {
            float dsc = dinv[xr];
            float m = 0.f;
#pragma unroll
            for (int cf = 0; cf < CF; cf++) {
#pragma unroll
                for (int j = 0; j < 4; j++) {
                    float v = acc[cf][j] * dsc;
                    acc[cf][j] = v;
                    m = fmaxf(m, fabsf(v));
                }
            }
            // row absmax across the 4 kq lanes holding this row
            m = fmaxf(m, __shfl_xor(m, 16, 64));
            m = fmaxf(m, __shfl_xor(m, 32, 64));
            float s = m * (1.0f / 127.0f);
            float inv = (m > 0.f) ? 127.0f / m : 0.f;

            unsigned int* Yr = Y8 + (size_t)xr * (NCOL / 4);
#pragma unroll
            for (int cf = 0; cf < CF; cf++) {
                unsigned int pk = 0;
#pragma unroll
                for (int j = 0; j < 4; j++) {
                    int qv = (int)rintf(acc[cf][j] * inv) + 128;
                    qv = min(max(qv, 0), 255);
                    pk |= (unsigned int)qv << (8 * j);
                }
                Yr[cf * 4 + kq] = pk;
            }
            if (kq == 0) scl[xr] = s;
        }
    }
}

// accumulate 8 uint8 feats with scale, tracking sum of scales (agg64: offset corrected later)
#define ACCQ(v, sc)                                          \
    scs += (sc);                                             \
    a0 = fmaf((float)((v).x & 0xffu), (sc), a0);             \
    a1 = fmaf((float)(((v).x >> 8) & 0xffu), (sc), a1);      \
    a2 = fmaf((float)(((v).x >> 16) & 0xffu), (sc), a2);     \
    a3 = fmaf((float)((v).x >> 24), (sc), a3);               \
    a4 = fmaf((float)((v).y & 0xffu), (sc), a4);             \
    a5 = fmaf((float)(((v).y >> 8) & 0xffu), (sc), a5);      \
    a6 = fmaf((float)(((v).y >> 16) & 0xffu), (sc), a6);     \
    a7 = fmaf((float)((v).y >> 24), (sc), a7);

// same without scale-sum: the uniform +128*Σs*di shift cancels in LayerNorm (shift-invariant)
#define ACCQN(v, sc)                                         \
    a0 = fmaf((float)((v).x & 0xffu), (sc), a0);             \
    a1 = fmaf((float)(((v).x >> 8) & 0xffu), (sc), a1);      \
    a2 = fmaf((float)(((v).x >> 16) & 0xffu), (sc), a2);     \
    a3 = fmaf((float)((v).x >> 24), (sc), a3);               \
    a4 = fmaf((float)((v).y & 0xffu), (sc), a4);             \
    a5 = fmaf((float)(((v).y >> 8) & 0xffu), (sc), a5);      \
    a6 = fmaf((float)(((v).y >> 16) & 0xffu), (sc), a6);     \
    a7 = fmaf((float)((v).y >> 24), (sc), a7);

// ---------------- fused aggregate + bias + LayerNorm + ReLU (128 int8 feats -> bf16) --------
// Quarter-wave q; lane l in [0,16) holds feats 8l..8l+7 (uint2 = 8 bytes of the 128B row).
// Streams 8 edges/iter (2 per quarter). u32 byte-offset gathers. No int8 offset correction.

__global__ __launch_bounds__(256) void agg_ln_kernel(
    const unsigned int* __restrict__ tmp, const float* __restrict__ scl,
    const int2* __restrict__ rinfo, const int* __restrict__ col,
    const float* __restrict__ dinv, const float* __restrict__ bias,
    const float* __restrict__ gamma, const float* __restrict__ beta,
    unsigned int* __restrict__ out, int n) {
    int wid = threadIdx.x >> 6;
    int lane = threadIdx.x & 63;
    int q = lane >> 4;
    int l = lane & 15;
    int stride = gridDim.x * 4;
    unsigned lb = (unsigned)l * 8u;  // lane byte offset within 128B row

    for (int node = blockIdx.x * 4 + wid; node < n; node += stride) {
        float di = dinv[node];
        int2 be = rinfo[node];
        int beg = __builtin_amdgcn_readfirstlane(be.x);
        int end = __builtin_amdgcn_readfirstlane(be.y);

        float a0 = 0.f, a1 = 0.f, a2 = 0.f, a3 = 0.f;
        float a4 = 0.f, a5 = 0.f, a6 = 0.f, a7 = 0.f;
        int e = beg;
#pragma unroll 2
        for (; e + 7 < end; e += 8) {
            int c0 = col[e], c1 = col[e + 1], c2 = col[e + 2], c3 = col[e + 3];
            int c4 = col[e + 4], c5 = col[e + 5], c6 = col[e + 6], c7 = col[e + 7];
            int sa = (q & 1) ? c1 : c0;
            int sb = (q & 1) ? c3 : c2;
            int s1 = (q & 2) ? sb : sa;
            int sc_ = (q & 1) ? c5 : c4;
            int sd = (q & 1) ? c7 : c6;
            int s2 = (q & 2) ? sd : sc_;
            uint2 v1 = ld_u2(tmp, (unsigned)s1 * 128u + lb);
            float f1 = ld_f(scl, (unsigned)s1 * 4u);
            uint2 v2 = ld_u2(tmp, (unsigned)s2 * 128u + lb);
            float f2 = ld_f(scl, (unsigned)s2 * 4u);
            ACCQN(v1, f1)
            ACCQN(v2, f2)
        }
        if (e + 3 < end) {
            int c0 = col[e], c1 = col[e + 1], c2 = col[e + 2], c3 = col[e + 3];
            int sa = (q & 1) ? c1 : c0;
            int sb = (q & 1) ? c3 : c2;
            int s = (q & 2) ? sb : sa;
            uint2 v = ld_u2(tmp, (unsigned)s * 128u + lb);
            float f = ld_f(scl, (unsigned)s * 4u);
            ACCQN(v, f)
            e += 4;
        }
        int rem = end - e;  // 0..3
        if (q < rem) {
            int s = col[e + q];
            uint2 v = ld_u2(tmp, (unsigned)s * 128u + lb);
            float f = ld_f(scl, (unsigned)s * 4u);
            ACCQN(v, f)
        }
        if (q == 3) {  // self loop
            uint2 v = ld_u2(tmp, (unsigned)node * 128u + lb);
            float f = ld_f(scl, (unsigned)node * 4u);
            ACCQN(v, f)
        }

        // combine quarters
        a0 += __shfl_xor(a0, 16, 64); a1 += __shfl_xor(a1, 16, 64);
        a2 += __shfl_xor(a2, 16, 64); a3 += __shfl_xor(a3, 16, 64);
        a4 += __shfl_xor(a4, 16, 64); a5 += __shfl_xor(a5, 16, 64);
        a6 += __shfl_xor(a6, 16, 64); a7 += __shfl_xor(a7, 16, 64);
        a0 += __shfl_xor(a0, 32, 64); a1 += __shfl_xor(a1, 32, 64);
        a2 += __shfl_xor(a2, 32, 64); a3 += __shfl_xor(a3, 32, 64);
        a4 += __shfl_xor(a4, 32, 64); a5 += __shfl_xor(a5, 32, 64);
        a6 += __shfl_xor(a6, 32, 64); a7 += __shfl_xor(a7, 32, 64);

        float4 b0 = ((const float4*)bias)[2 * l];
        float4 b1 = ((const float4*)bias)[2 * l + 1];
        a0 = fmaf(a0, di, b0.x); a1 = fmaf(a1, di, b0.y);
        a2 = fmaf(a2, di, b0.z); a3 = fmaf(a3, di, b0.w);
        a4 = fmaf(a4, di, b1.x); a5 = fmaf(a5, di, b1.y);
        a6 = fmaf(a6, di, b1.z); a7 = fmaf(a7, di, b1.w);

        // LayerNorm across 16 lanes (all quarters hold identical data)
        float s8 = a0 + a1 + a2 + a3 + a4 + a5 + a6 + a7;
#pragma unroll
        for (int m = 1; m < 16; m <<= 1) s8 += __shfl_xor(s8, m, 64);
        float mu = s8 * (1.0f / 128.0f);
        float d0 = a0 - mu, d1 = a1 - mu, d2 = a2 - mu, d3 = a3 - mu;
        float d4 = a4 - mu, d5 = a5 - mu, d6 = a6 - mu, d7 = a7 - mu;
        float vv = d0 * d0 + d1 * d1 + d2 * d2 + d3 * d3 +
                   d4 * d4 + d5 * d5 + d6 * d6 + d7 * d7;
#pragma unroll
        for (int m = 1; m < 16; m <<= 1) vv += __shfl_xor(vv, m, 64);
        float r = rsqrtf(vv * (1.0f / 128.0f) + 1e-5f);

        if (lane < 16) {
            float4 g0 = ((const float4*)gamma)[2 * l];
            float4 g1 = ((const float4*)gamma)[2 * l + 1];
            float4 e0 = ((const float4*)beta)[2 * l];
            float4 e1 = ((const float4*)beta)[2 * l + 1];
            float o0 = fmaxf(fmaf(d0 * r, g0.x, e0.x), 0.f);
            float o1 = fmaxf(fmaf(d1 * r, g0.y, e0.y), 0.f);
            float o2 = fmaxf(fmaf(d2 * r, g0.z, e0.z), 0.f);
            float o3 = fmaxf(fmaf(d3 * r, g0.w, e0.w), 0.f);
            float o4 = fmaxf(fmaf(d4 * r, g1.x, e1.x), 0.f);
            float o5 = fmaxf(fmaf(d5 * r, g1.y, e1.y), 0.f);
            float o6 = fmaxf(fmaf(d6 * r, g1.z, e1.z), 0.f);
            float o7 = fmaxf(fmaf(d7 * r, g1.w, e1.w), 0.f);
            uint4 o = make_uint4(pack_bf2(o0, o1), pack_bf2(o2, o3),
                                 pack_bf2(o4, o5), pack_bf2(o6, o7));
            ((uint4*)out)[(size_t)node * 16 + l] = o;
        }
    }
}

// ---------------- final aggregate + bias (64 int8 feats -> fp32, no LN) ----------------
// Eighth-wave oc; lane l in [0,8) holds feats 8l..8l+7 (uint2 of the 64B row).

__global__ __launch_bounds__(256) void agg64_kernel(
    const unsigned int* __restrict__ tmp, const float* __restrict__ scl,
    const int2* __restrict__ rinfo, const int* __restrict__ col,
    const float* __restrict__ dinv, const float* __restrict__ bias,
    float* __restrict__ out, int n) {
    int wid = threadIdx.x >> 6;
    int lane = threadIdx.x & 63;
    int oc = lane >> 3;
    int l = lane & 7;
    int stride = gridDim.x * 4;
    unsigned lb = (unsigned)l * 8u;  // lane byte offset within 64B row

    for (int node = blockIdx.x * 4 + wid; node < n; node += stride) {
        float di = dinv[node];
        int2 be = rinfo[node];
        int beg = __builtin_amdgcn_readfirstlane(be.x);
        int end = __builtin_amdgcn_readfirstlane(be.y);

        float a0 = 0.f, a1 = 0.f, a2 = 0.f, a3 = 0.f;
        float a4 = 0.f, a5 = 0.f, a6 = 0.f, a7 = 0.f;
        float scs = 0.f;
        int e = beg;
#pragma unroll 2
        for (; e + 7 < end; e += 8) {
            int c0 = col[e], c1 = col[e + 1], c2 = col[e + 2], c3 = col[e + 3];
            int c4 = col[e + 4], c5 = col[e + 5], c6 = col[e + 6], c7 = col[e + 7];
            int sa = (oc & 1) ? c1 : c0;
            int sb = (oc & 1) ? c3 : c2;
            int sc_ = (oc & 1) ? c5 : c4;
            int sd = (oc & 1) ? c7 : c6;
            int sab = (oc & 2) ? sb : sa;
            int scd = (oc & 2) ? sd : sc_;
            int s = (oc & 4) ? scd : sab;
            uint2 v = ld_u2(tmp, (unsigned)s * 64u + lb);
            float f = ld_f(scl, (unsigned)s * 4u);
            ACCQ(v, f)
        }
        int rem = end - e;  // 0..7, oc==7 never takes tail
        if (oc < rem) {
            int s = col[e + oc];
            uint2 v = ld_u2(tmp, (unsigned)s * 64u + lb);
            float f = ld_f(scl, (unsigned)s * 4u);
            ACCQ(v, f)
        }
        if (oc == 7) {  // self loop
            uint2 v = ld_u2(tmp, (unsigned)node * 64u + lb);
            float f = ld_f(scl, (unsigned)node * 4u);
            ACCQ(v, f)
        }
        a0 = fmaf(-128.f, scs, a0); a1 = fmaf(-128.f, scs, a1);
        a2 = fmaf(-128.f, scs, a2); a3 = fmaf(-128.f, scs, a3);
        a4 = fmaf(-128.f, scs, a4); a5 = fmaf(-128.f, scs, a5);
        a6 = fmaf(-128.f, scs, a6); a7 = fmaf(-128.f, scs, a7);

        a0 += __shfl_xor(a0, 8, 64);  a1 += __shfl_xor(a1, 8, 64);
        a2 += __shfl_xor(a2, 8, 64);  a3 += __shfl_xor(a3, 8, 64);
        a4 += __shfl_xor(a4, 8, 64);  a5 += __shfl_xor(a5, 8, 64);
        a6 += __shfl_xor(a6, 8, 64);  a7 += __shfl_xor(a7, 8, 64);
        a0 += __shfl_xor(a0, 16, 64); a1 += __shfl_xor(a1, 16, 64);
        a2 += __shfl_xor(a2, 16, 64); a3 += __shfl_xor(a3, 16, 64);
        a4 += __shfl_xor(a4, 16, 64); a5 += __shfl_xor(a5, 16, 64);
        a6 += __shfl_xor(a6, 16, 64); a7 += __shfl_xor(a7, 16, 64);
        a0 += __shfl_xor(a0, 32, 64); a1 += __shfl_xor(a1, 32, 64);
        a2 += __shfl_xor(a2, 32, 64); a3 += __shfl_xor(a3, 32, 64);
        a4 += __shfl_xor(a4, 32, 64); a5 += __shfl_xor(a5, 32, 64);
        a6 += __shfl_xor(a6, 32, 64); a7 += __shfl_xor(a7, 32, 64);

        if (lane < 8) {
            float4 b0 = ((const float4*)bias)[2 * l];
            float4 b1 = ((const float4*)bias)[2 * l + 1];
            float4 o0, o1;
            o0.x = fmaf(a0, di, b0.x); o0.y = fmaf(a1, di, b0.y);
            o0.z = fmaf(a2, di, b0.z); o0.w = fmaf(a3, di, b0.w);
            o1.x = fmaf(a4, di, b1.x); o1.y = fmaf(a5, di, b1.y);
            o1.z = fmaf(a6, di, b1.z); o1.w = fmaf(a7, di, b1.w);
            ((float4*)out)[(size_t)node * 16 + 2 * l] = o0;
            ((float4*)out)[(size_t)node * 16 + 2 * l + 1] = o1;
        }
    }
}

// ---------------- launch ----------------

extern "C" void kernel_launch(void* const* d_in, const int* in_sizes, int n_in,
                              void* d_out, int out_size, void* d_ws, size_t ws_size,
                              hipStream_t stream) {
    const float* x   = (const float*)d_in[0];
    const int*   ei  = (const int*)d_in[1];
    const float* W1  = (const float*)d_in[2];
    const float* b1  = (const float*)d_in[3];
    const float* g1  = (const float*)d_in[4];
    const float* be1 = (const float*)d_in[5];
    const float* W2  = (const float*)d_in[6];
    const float* b2  = (const float*)d_in[7];
    const float* g2  = (const float*)d_in[8];
    const float* be2 = (const float*)d_in[9];
    const float* W3  = (const float*)d_in[10];
    const float* b3  = (const float*)d_in[11];

    int n = in_sizes[0] / 128;
    int E = in_sizes[1] / 2;
    const int* src = ei;
    const int* dst = ei + E;
    int nbuck = (n + BSIZE - 1) / BSIZE;  // 196 for n=100000 (n must be < 131072)

    char* p = (char*)d_ws;
    auto alloc = [&](size_t bytes) {
        void* q = (void*)p;
        p += (bytes + 255) & ~(size_t)255;
        return q;
    };
    int*   bfill   = (int*)alloc(256 * 4);
    int2*  rinfo   = (int2*)alloc((size_t)n * 8);
    float* dinv    = (float*)alloc((size_t)n * 4);
    float* scl     = (float*)alloc((size_t)n * 4);
    unsigned short* wsw1 = (unsigned short*)alloc(128 * 128 * 2);
    unsigned short* wsw2 = (unsigned short*)alloc(128 * 128 * 2);
    unsigned short* wsw3 = (unsigned short*)alloc(64 * 128 * 2);
    int*   region  = (int*)alloc((size_t)nbuck * CAP * 4);
    int*   col     = (int*)alloc((size_t)nbuck * CAP * 4);
    unsigned int* bufA = (unsigned int*)alloc((size_t)n * 64 * 4);  // LN out, n x 128 bf16
    unsigned int* bufB = (unsigned int*)alloc((size_t)n * 32 * 4);  // GEMM out, n x 128 int8

    // setup: W convert (blocks 0..159) + bfill zero (block 160)
    wconv_kernel<<<161, 256, 0, stream>>>(W1, W2, W3, wsw1, wsw2, wsw3, bfill);

    int bin_blocks = (E + CHUNK - 1) / CHUNK;
    bin_kernel<<<bin_blocks, 256, 0, stream>>>(src, dst, E, region, bfill);
    build_kernel<<<nbuck, 512, 0, stream>>>(region, bfill, rinfo, dinv, col, n);

    int gemm_blocks = (n + 127) / 128;
    int agg_blocks = 2048;  // exactly 8 blocks/CU = 32 waves resident in one round

    // layer 1
    mfma_gemm_kernel<128, true><<<gemm_blocks, 256, 0, stream>>>(x, wsw1, dinv, bufB, scl, n);
    agg_ln_kernel<<<agg_blocks, 256, 0, stream>>>(bufB, scl, rinfo, col, dinv, b1, g1, be1, bufA, n);

    // layer 2
    mfma_gemm_kernel<128, false><<<gemm_blocks, 256, 0, stream>>>(bufA, wsw2, dinv, bufB, scl, n);
    agg_ln_kernel<<<agg_blocks, 256, 0, stream>>>(bufB, scl, rinfo, col, dinv, b2, g2, be2, bufA, n);

    // layer 3
    mfma_gemm_kernel<64, false><<<gemm_blocks, 256, 0, stream>>>(bufA, wsw3, dinv, bufB, scl, n);
    agg64_kernel<<<agg_blocks, 256, 0, stream>>>(bufB, scl, rinfo, col, dinv, b3, (float*)d_out, n);
}